// Round 15
// baseline (109.508 us; speedup 1.0000x reference)
//
#include <hip/hip_runtime.h>

#define NGRAPH 48
#define ALPHA 1.44269504088896340736f   // log2(e)
#define LN2   0.69314718055994530942f

typedef __bf16 bf16x8 __attribute__((ext_vector_type(8)));
typedef float  f32x16 __attribute__((ext_vector_type(16)));

__device__ __forceinline__ f32x16 MFMA(bf16x8 a, bf16x8 b, f32x16 c) {
  return __builtin_amdgcn_mfma_f32_32x32x16_bf16(a, b, c, 0, 0, 0);
}

__device__ __forceinline__ float fsilu(float x) {      // plain silu
  return x * __builtin_amdgcn_rcpf(1.0f + __expf(-x));
}
// s = ALPHA*x; returns ALPHA*silu(x). exp2(-s) == exp(-x); neg folds into v_exp.
__device__ __forceinline__ float ssilu(float s) {
  return s * __builtin_amdgcn_rcpf(1.0f + __builtin_amdgcn_exp2f(-s));
}

// ---------------- prep: weights -> bf16 [n][k] transposed (+ scale folds) -------
__global__ __launch_bounds__(256) void prep_kernel(
    const float* We1, const float* We2, const float* Wn1, const float* Wn2,
    __bf16* We1T, __bf16* We2T, __bf16* Wn1T, __bf16* Wn2T, float* wv) {
  int i = blockIdx.x * 256 + threadIdx.x;
  const int S0 = 3 * 256 * 128;   // We1T [l][n'(256)][k(128)]  (unscaled)
  const int S1 = 3 * 128 * 128;   // We2T [l][n][k]             (unscaled: alpha*ln2=1)
  const int S2 = 3 * 128 * 256;   // Wn1T [l][n][k(256)]        (agg half *LN2)
  const int S3 = 3 * 128 * 128;   // Wn2T [l][n][k]             (unscaled)
  const int S4 = 3 * 128;         // wv   [l][k] = ALPHA*We1[l][256][k]
  if (i < S0) {
    int l = i / (256 * 128); int r = i % (256 * 128); int n = r / 128; int k = r % 128;
    float v = (n < 128) ? We1[(l * 257 + k) * 128 + n]
                        : We1[(l * 257 + 128 + k) * 128 + (n - 128)];
    We1T[i] = (__bf16)v; return;
  }
  i -= S0;
  if (i < S1) {
    int l = i / (128 * 128); int r = i % (128 * 128); int n = r / 128, k = r % 128;
    We2T[i] = (__bf16)We2[(l * 128 + k) * 128 + n]; return;
  }
  i -= S1;
  if (i < S2) {
    int l = i / (128 * 256); int r = i % (128 * 256); int n = r / 256, k = r % 256;
    float sc = (k >= 128) ? LN2 : 1.0f;
    Wn1T[i] = (__bf16)(Wn1[(l * 256 + k) * 128 + n] * sc); return;
  }
  i -= S2;
  if (i < S3) {
    int l = i / (128 * 128); int r = i % (128 * 128); int n = r / 128, k = r % 128;
    Wn2T[i] = (__bf16)Wn2[(l * 128 + k) * 128 + n]; return;
  }
  i -= S3;
  if (i < S4) {
    int l = i / 128, k = i % 128;
    wv[i] = ALPHA * We1[(l * 257 + 256) * 128 + k];
  }
}

// ---- from 32 rows of h (f32 LDS, stride 132) emit prescaled P''(f32), Q''(bf16)
__device__ __forceinline__ void pq_stage(const float* hn,
    const __bf16* We1Tl, const float* be1l, float* Pp, __bf16* Qb, int r0, int t) {
  int lane = t & 63, wid = t >> 6;
  int l31 = lane & 31, q = lane >> 5;
  bf16x8 af[8];
#pragma unroll
  for (int kk = 0; kk < 8; ++kk) {
    int k0 = kk * 16 + q * 8;
    const float* ap = &hn[l31 * 132 + k0];
#pragma unroll
    for (int j = 0; j < 8; ++j) af[kk][j] = (__bf16)ap[j];
  }
#pragma unroll
  for (int half = 0; half < 2; ++half) {
    int nt = wid * 2 + half;
    f32x16 acc;
#pragma unroll
    for (int r = 0; r < 16; ++r) acc[r] = 0.f;
#pragma unroll
    for (int kk = 0; kk < 8; ++kk) {
      int k0 = kk * 16 + q * 8;
      bf16x8 b = *(const bf16x8*)&We1Tl[(nt * 32 + l31) * 128 + k0];
      acc = MFMA(af[kk], b, acc);
    }
    int col = nt * 32 + l31;
    if (col < 128) {
      float bb = be1l[col];
#pragma unroll
      for (int reg = 0; reg < 16; ++reg) {
        int rr = (reg & 3) + 8 * (reg >> 2) + 4 * q;
        Pp[(r0 + rr) * 128 + col] = (acc[reg] + bb) * ALPHA;
      }
    } else {
      int c2 = col - 128;
#pragma unroll
      for (int reg = 0; reg < 16; ++reg) {
        int rr = (reg & 3) + 8 * (reg >> 2) + 4 * q;
        Qb[(r0 + rr) * 128 + c2] = (__bf16)(acc[reg] * ALPHA);
      }
    }
  }
}

// ---------------- embed: h0 = [H,beta,sin,cos]@W_emb + b_emb; then P0,Q0 -------
__global__ __launch_bounds__(256) void embed_kernel(
    const float* H, const float* beta, const float* W_emb, const float* b_emb,
    const __bf16* We1T0, const float* be1_0,
    float* h, float* Pp, __bf16* Qb) {
  __shared__ float Hs[256];
  __shared__ float bet[32], sb[32], cb[32];
  __shared__ float hns[32 * 132];
  int t = threadIdx.x; int r0 = blockIdx.x * 32;
  Hs[t] = H[r0 * 8 + t];
  if (t < 32) {
    float b = beta[r0 + t];
    bet[t] = b; sb[t] = sinf(b); cb[t] = cosf(b);
  }
  __syncthreads();
#pragma unroll
  for (int i = 0; i < 16; ++i) {
    int c = t + 256 * i;
    int row = c >> 7, n = c & 127;
    float acc = b_emb[n];
#pragma unroll
    for (int k = 0; k < 8; ++k) acc += Hs[row * 8 + k] * W_emb[k * 128 + n];
    acc += bet[row] * W_emb[8 * 128 + n] + sb[row] * W_emb[9 * 128 + n]
         + cb[row] * W_emb[10 * 128 + n];
    hns[row * 132 + n] = acc;
    h[(r0 + row) * 128 + n] = acc;
  }
  __syncthreads();
  pq_stage(hns, We1T0, be1_0, Pp, Qb, r0, t);
}

// ---------------- edge kernel: 6 waves/SIMD single-round variant ---------------
// grid = 768 = 3 blocks/CU x 256 CU (ONE round). LDS diet to 53568B (<= 54613):
// full WeTs resident (NO r12 restaging), Ps/Qs/Zs staged; wvg/be2l read from
// global (uniform/coalesced, L1/L2-hot); agg b-half combine moved to GLOBAL
// partials (agg0/agg1; node sums) -> aggp LDS + final barrier deleted.
// Register diet for the 85-VGPR @6w/EU budget: single f32x16 acc, af[8] = ~78 live.
// Failure signatures (per r5/6/9/13): VGPR ~44 (AGPR thrash) or WRITE_SIZE >> 5MB
// (spill) -> revert to r10 structure.
__global__ __launch_bounds__(512)
__attribute__((amdgpu_waves_per_eu(6, 6)))
void edge_kernel(
    const float* __restrict__ Ppin, const __bf16* __restrict__ Qbin,
    const float* __restrict__ Z, const float* __restrict__ wvg,
    const __bf16* __restrict__ We2Tl, const float* __restrict__ be2l,
    float* __restrict__ agg0, float* __restrict__ agg1) {
  __shared__ __bf16 Qs[64 * 132];     // 16896 B
  __shared__ __bf16 WeTs[128 * 132];  // 33792 B
  __shared__ float  Ps[4 * 132];      // 2112 B
  __shared__ float  Zs[192];          // 768 B   -> total 53568 B
  int t = threadIdx.x;
  int g = blockIdx.x >> 4, atile = blockIdx.x & 15;
  int a0 = atile * 4, gn0 = g * 64;
#pragma unroll
  for (int i = 0; i < 2; ++i) {
    int c = t + 512 * i; int row = c >> 4, c8 = (c & 15) * 8;
    *(uint4*)&Qs[row * 132 + c8] = *(const uint4*)&Qbin[(gn0 + row) * 128 + c8];
  }
#pragma unroll
  for (int i = 0; i < 4; ++i) {
    int c = t + 512 * i; int row = c >> 4, c8 = (c & 15) * 8;
    *(uint4*)&WeTs[row * 132 + c8] = *(const uint4*)&We2Tl[row * 128 + c8];
  }
  if (t < 128) {
    int row = t >> 5, c4 = (t & 31) * 4;
    *(float4*)&Ps[row * 132 + c4] = *(const float4*)&Ppin[(gn0 + a0 + row) * 128 + c4];
  }
  if (t < 192) Zs[t] = Z[gn0 * 3 + t];
  __syncthreads();

  int lane = t & 63, wid = t >> 6, l31 = lane & 31, q = lane >> 5;
  int a_loc = wid >> 1, bhalf = wid & 1;
  int a_g = a0 + a_loc;
  int b = bhalf * 32 + l31;

  float zax = Zs[a_g * 3], zay = Zs[a_g * 3 + 1], zaz = Zs[a_g * 3 + 2];
  float dx = zax - Zs[b * 3], dy = zay - Zs[b * 3 + 1], dz = zaz - Zs[b * 3 + 2];
  float d2 = dx * dx + dy * dy + dz * dz;

  // build m1 A-fragments: m1[b][k] = ssilu(P'' + Q'' + d2*w'')
  bf16x8 af[8];
#pragma unroll
  for (int kk = 0; kk < 8; ++kk) {
    int k0 = kk * 16 + q * 8;
    float4 pv0 = *(const float4*)&Ps[a_loc * 132 + k0];
    float4 pv1 = *(const float4*)&Ps[a_loc * 132 + k0 + 4];
    float4 wv0 = *(const float4*)&wvg[k0];        // global, quarter-group-uniform
    float4 wv1 = *(const float4*)&wvg[k0 + 4];
    bf16x8 qv = *(const bf16x8*)&Qs[b * 132 + k0];
#pragma unroll
    for (int j = 0; j < 4; ++j) {
      af[kk][j]     = (__bf16)ssilu(fmaf(d2, wv0[j], pv0[j]) + (float)qv[j]);
      af[kk][j + 4] = (__bf16)ssilu(fmaf(d2, wv1[j], pv1[j]) + (float)qv[j + 4]);
    }
  }
  // 4 sequential nt rounds, SINGLE acc (register diet for 6 waves/EU)
  float smv[4];
#pragma unroll
  for (int nt = 0; nt < 4; ++nt) {
    f32x16 acc;
#pragma unroll
    for (int r = 0; r < 16; ++r) acc[r] = 0.f;
#pragma unroll
    for (int kk = 0; kk < 8; ++kk) {
      int ko = kk * 16 + q * 8;
      acc = MFMA(af[kk], *(const bf16x8*)&WeTs[(nt * 32 + l31) * 132 + ko], acc);
    }
    float bb = ALPHA * be2l[nt * 32 + l31];       // global, coalesced, L2-hot
    float s0 = 0.f, s1 = 0.f;
#pragma unroll
    for (int r = 0; r < 8; ++r) { s0 += ssilu(acc[r] + bb); s1 += ssilu(acc[r + 8] + bb); }
    float s = s0 + s1; s += __shfl_xor(s, 32);
    smv[nt] = s;
  }
  // write per-b-half partials straight to global (node sums agg0+agg1)
  if (q == 0) {
    float* ap = bhalf ? agg1 : agg0;
#pragma unroll
    for (int nt = 0; nt < 4; ++nt)
      ap[(gn0 + a_g) * 128 + nt * 32 + l31] = smv[nt];
  }
}

// ---------------- node update (32 rows/block, grid 96; r10 version) ------------
__global__ __launch_bounds__(256) void node_kernel(
    const float* __restrict__ h,
    const float* __restrict__ agg0, const float* __restrict__ agg1,
    const __bf16* __restrict__ Wn1Tl, const float* __restrict__ bn1l,
    const __bf16* __restrict__ Wn2Tl, const float* __restrict__ bn2l,
    const __bf16* __restrict__ We1Tn, const float* __restrict__ be1n,
    float* __restrict__ hout, float* __restrict__ Pp, __bf16* __restrict__ Qb,
    int do_pq) {
  __shared__ float A1s[32 * 260];   // [h | ALPHA*agg] rows
  __shared__ float T1s[32 * 132];
  __shared__ float hns[32 * 132];
  int t = threadIdx.x; int r0 = blockIdx.x * 32;
  int lane = t & 63, wid = t >> 6, l31 = lane & 31, q = lane >> 5;
#pragma unroll
  for (int i = 0; i < 8; ++i) {
    int c = t + 256 * i;              // 2048 float4 chunks
    int row = c >> 6, c4 = (c & 63) * 4;
    if (c4 < 128) {
      *(float4*)&A1s[row * 260 + c4] = *(const float4*)&h[(r0 + row) * 128 + c4];
    } else {
      float4 x = *(const float4*)&agg0[(r0 + row) * 128 + c4 - 128];
      float4 y = *(const float4*)&agg1[(r0 + row) * 128 + c4 - 128];
      x.x += y.x; x.y += y.y; x.z += y.z; x.w += y.w;
      *(float4*)&A1s[row * 260 + c4] = x;
    }
  }
  __syncthreads();
  // stage 1: T1 = silu([h,agg]@Wn1 + bn1), K=256 (agg half of Wn1T pre-scaled LN2)
  {
    f32x16 acc;
#pragma unroll
    for (int r = 0; r < 16; ++r) acc[r] = 0.f;
#pragma unroll
    for (int kk = 0; kk < 16; ++kk) {
      int k0 = kk * 16 + q * 8;
      bf16x8 a; const float* ap = &A1s[l31 * 260 + k0];
#pragma unroll
      for (int j = 0; j < 8; ++j) a[j] = (__bf16)ap[j];
      bf16x8 b = *(const bf16x8*)&Wn1Tl[(wid * 32 + l31) * 256 + k0];
      acc = MFMA(a, b, acc);
    }
    int col = wid * 32 + l31; float bb = bn1l[col];
#pragma unroll
    for (int reg = 0; reg < 16; ++reg) {
      int rr = (reg & 3) + 8 * (reg >> 2) + 4 * q;
      T1s[rr * 132 + col] = fsilu(acc[reg] + bb);
    }
  }
  __syncthreads();
  // stage 2: h_new = h + T1@Wn2 + bn2
  {
    f32x16 acc;
#pragma unroll
    for (int r = 0; r < 16; ++r) acc[r] = 0.f;
#pragma unroll
    for (int kk = 0; kk < 8; ++kk) {
      int k0 = kk * 16 + q * 8;
      bf16x8 a; const float* ap = &T1s[l31 * 132 + k0];
#pragma unroll
      for (int j = 0; j < 8; ++j) a[j] = (__bf16)ap[j];
      bf16x8 b = *(const bf16x8*)&Wn2Tl[(wid * 32 + l31) * 128 + k0];
      acc = MFMA(a, b, acc);
    }
    int col = wid * 32 + l31; float bb = bn2l[col];
#pragma unroll
    for (int reg = 0; reg < 16; ++reg) {
      int rr = (reg & 3) + 8 * (reg >> 2) + 4 * q;
      float v = acc[reg] + bb + A1s[rr * 260 + col];
      hns[rr * 132 + col] = v;
      hout[(r0 + rr) * 128 + col] = v;
    }
  }
  __syncthreads();
  if (do_pq) pq_stage(hns, We1Tn, be1n, Pp, Qb, r0, t);
}

// ---------------- readout: segsum/8 -> silu -> Wo1 -> silu -> Wo2 ----------
__global__ __launch_bounds__(256) void readout_kernel(
    const float* h, const float* Wo1, const float* bo1,
    const float* Wo2, const float* bo2, float* out) {
  __shared__ float part[2][128];
  __shared__ float sbuf[128];
  int g = blockIdx.x; int t = threadIdx.x; int n = t & 127, half = t >> 7;
  float acc = 0.f;
#pragma unroll
  for (int r = 0; r < 32; ++r) acc += h[(g * 64 + half * 32 + r) * 128 + n];
  part[half][n] = acc;
  __syncthreads();
  if (half == 0) sbuf[n] = fsilu((part[0][n] + part[1][n]) * 0.125f);
  __syncthreads();
  float o1 = 0.f;
#pragma unroll
  for (int k = 0; k < 64; ++k) o1 += sbuf[half * 64 + k] * Wo1[(half * 64 + k) * 128 + n];
  part[half][n] = o1;
  __syncthreads();
  if (half == 0) sbuf[n] = fsilu(part[0][n] + part[1][n] + bo1[n]);
  __syncthreads();
  float o2 = 0.f;
#pragma unroll
  for (int k = 0; k < 64; ++k) o2 += sbuf[half * 64 + k] * Wo2[(half * 64 + k) * 128 + n];
  part[half][n] = o2;
  __syncthreads();
  if (half == 0) out[g * 128 + n] = part[0][n] + part[1][n] + bo2[n];
}

extern "C" void kernel_launch(void* const* d_in, const int* in_sizes, int n_in,
                              void* d_out, int out_size, void* d_ws, size_t ws_size,
                              hipStream_t stream) {
  (void)in_sizes; (void)n_in; (void)out_size; (void)ws_size;
  const float* H     = (const float*)d_in[0];
  const float* Z     = (const float*)d_in[1];
  const float* beta  = (const float*)d_in[2];
  const float* W_emb = (const float*)d_in[5];
  const float* b_emb = (const float*)d_in[6];
  const float* We1   = (const float*)d_in[7];
  const float* be1   = (const float*)d_in[8];
  const float* We2   = (const float*)d_in[9];
  const float* be2   = (const float*)d_in[10];
  const float* Wn1   = (const float*)d_in[11];
  const float* bn1   = (const float*)d_in[12];
  const float* Wn2   = (const float*)d_in[13];
  const float* bn2   = (const float*)d_in[14];
  const float* Wo1   = (const float*)d_in[15];
  const float* bo1   = (const float*)d_in[16];
  const float* Wo2   = (const float*)d_in[17];
  const float* bo2   = (const float*)d_in[18];

  char* ws = (char*)d_ws;
  float*  h    = (float*)(ws + 0);          // 1.57 MB
  float*  Pp   = (float*)(ws + 1572864);    // 1.57 MB
  float*  agg0 = (float*)(ws + 3145728);    // 1.57 MB (b-half 0 partial)
  float*  agg1 = (float*)(ws + 4718592);    // 1.57 MB (b-half 1 partial)
  __bf16* Qb   = (__bf16*)(ws + 6291456);   // 0.79 MB
  __bf16* We1T = (__bf16*)(ws + 7077888);
  __bf16* We2T = (__bf16*)(ws + 7274496);
  __bf16* Wn1T = (__bf16*)(ws + 7372800);
  __bf16* Wn2T = (__bf16*)(ws + 7569408);
  float*  wv   = (float*)(ws + 7667712);

  prep_kernel<<<1154, 256, 0, stream>>>(We1, We2, Wn1, Wn2, We1T, We2T, Wn1T, Wn2T, wv);
  embed_kernel<<<96, 256, 0, stream>>>(H, beta, W_emb, b_emb, We1T, be1, h, Pp, Qb);

  for (int l = 0; l < 3; ++l) {
    edge_kernel<<<NGRAPH * 16, 512, 0, stream>>>(
        Pp, Qb, Z, wv + l * 128, We2T + l * 128 * 128, be2 + l * 128, agg0, agg1);
    int dopq = (l < 2) ? 1 : 0;
    node_kernel<<<96, 256, 0, stream>>>(
        h, agg0, agg1,
        Wn1T + l * 128 * 256, bn1 + l * 128, Wn2T + l * 128 * 128, bn2 + l * 128,
        We1T + (dopq ? (l + 1) * 256 * 128 : 0), be1 + (dopq ? (l + 1) * 128 : 0),
        h, Pp, Qb, dopq);
  }
  readout_kernel<<<NGRAPH, 256, 0, stream>>>(h, Wo1, bo1, Wo2, bo2, (float*)d_out);
}

// Round 16
// 100.708 us; speedup vs baseline: 1.0874x; 1.0874x over previous
//
#include <hip/hip_runtime.h>

#define NGRAPH 48
#define ALPHA 1.44269504088896340736f   // log2(e)
#define LN2   0.69314718055994530942f

typedef __bf16 bf16x8 __attribute__((ext_vector_type(8)));
typedef float  f32x16 __attribute__((ext_vector_type(16)));

__device__ __forceinline__ f32x16 MFMA(bf16x8 a, bf16x8 b, f32x16 c) {
  return __builtin_amdgcn_mfma_f32_32x32x16_bf16(a, b, c, 0, 0, 0);
}

__device__ __forceinline__ float fsilu(float x) {      // plain silu
  return x * __builtin_amdgcn_rcpf(1.0f + __expf(-x));
}
// s = ALPHA*x; returns ALPHA*silu(x). exp2(-s) == exp(-x); neg folds into v_exp.
__device__ __forceinline__ float ssilu(float s) {
  return s * __builtin_amdgcn_rcpf(1.0f + __builtin_amdgcn_exp2f(-s));
}

// ---------------- prep: weights -> bf16 [n][k] transposed (+ scale folds) -------
__global__ __launch_bounds__(256) void prep_kernel(
    const float* We1, const float* We2, const float* Wn1, const float* Wn2,
    __bf16* We1T, __bf16* We2T, __bf16* Wn1T, __bf16* Wn2T, float* wv) {
  int i = blockIdx.x * 256 + threadIdx.x;
  const int S0 = 3 * 256 * 128;   // We1T [l][n'(256)][k(128)]  (unscaled)
  const int S1 = 3 * 128 * 128;   // We2T [l][n][k]             (unscaled: alpha*ln2=1)
  const int S2 = 3 * 128 * 256;   // Wn1T [l][n][k(256)]        (agg half *LN2)
  const int S3 = 3 * 128 * 128;   // Wn2T [l][n][k]             (unscaled)
  const int S4 = 3 * 128;         // wv   [l][k] = ALPHA*We1[l][256][k]
  if (i < S0) {
    int l = i / (256 * 128); int r = i % (256 * 128); int n = r / 128; int k = r % 128;
    float v = (n < 128) ? We1[(l * 257 + k) * 128 + n]
                        : We1[(l * 257 + 128 + k) * 128 + (n - 128)];
    We1T[i] = (__bf16)v; return;
  }
  i -= S0;
  if (i < S1) {
    int l = i / (128 * 128); int r = i % (128 * 128); int n = r / 128, k = r % 128;
    We2T[i] = (__bf16)We2[(l * 128 + k) * 128 + n]; return;
  }
  i -= S1;
  if (i < S2) {
    int l = i / (128 * 256); int r = i % (128 * 256); int n = r / 256, k = r % 256;
    float sc = (k >= 128) ? LN2 : 1.0f;
    Wn1T[i] = (__bf16)(Wn1[(l * 256 + k) * 128 + n] * sc); return;
  }
  i -= S2;
  if (i < S3) {
    int l = i / (128 * 128); int r = i % (128 * 128); int n = r / 128, k = r % 128;
    Wn2T[i] = (__bf16)Wn2[(l * 128 + k) * 128 + n]; return;
  }
  i -= S3;
  if (i < S4) {
    int l = i / 128, k = i % 128;
    wv[i] = ALPHA * We1[(l * 257 + 256) * 128 + k];
  }
}

// ---- from 32 rows of h (f32 LDS, stride 132) emit prescaled P''(f32), Q''(bf16)
__device__ __forceinline__ void pq_stage(const float* hn,
    const __bf16* We1Tl, const float* be1l, float* Pp, __bf16* Qb, int r0, int t) {
  int lane = t & 63, wid = t >> 6;
  int l31 = lane & 31, q = lane >> 5;
  bf16x8 af[8];
#pragma unroll
  for (int kk = 0; kk < 8; ++kk) {
    int k0 = kk * 16 + q * 8;
    const float* ap = &hn[l31 * 132 + k0];
#pragma unroll
    for (int j = 0; j < 8; ++j) af[kk][j] = (__bf16)ap[j];
  }
#pragma unroll
  for (int half = 0; half < 2; ++half) {
    int nt = wid * 2 + half;
    f32x16 acc;
#pragma unroll
    for (int r = 0; r < 16; ++r) acc[r] = 0.f;
#pragma unroll
    for (int kk = 0; kk < 8; ++kk) {
      int k0 = kk * 16 + q * 8;
      bf16x8 b = *(const bf16x8*)&We1Tl[(nt * 32 + l31) * 128 + k0];
      acc = MFMA(af[kk], b, acc);
    }
    int col = nt * 32 + l31;
    if (col < 128) {
      float bb = be1l[col];
#pragma unroll
      for (int reg = 0; reg < 16; ++reg) {
        int rr = (reg & 3) + 8 * (reg >> 2) + 4 * q;
        Pp[(r0 + rr) * 128 + col] = (acc[reg] + bb) * ALPHA;
      }
    } else {
      int c2 = col - 128;
#pragma unroll
      for (int reg = 0; reg < 16; ++reg) {
        int rr = (reg & 3) + 8 * (reg >> 2) + 4 * q;
        Qb[(r0 + rr) * 128 + c2] = (__bf16)(acc[reg] * ALPHA);
      }
    }
  }
}

// ---------------- embed: h0 = [H,beta,sin,cos]@W_emb + b_emb; then P0,Q0 -------
__global__ __launch_bounds__(256) void embed_kernel(
    const float* H, const float* beta, const float* W_emb, const float* b_emb,
    const __bf16* We1T0, const float* be1_0,
    float* h, float* Pp, __bf16* Qb) {
  __shared__ float Hs[256];
  __shared__ float bet[32], sb[32], cb[32];
  __shared__ float hns[32 * 132];
  int t = threadIdx.x; int r0 = blockIdx.x * 32;
  Hs[t] = H[r0 * 8 + t];
  if (t < 32) {
    float b = beta[r0 + t];
    bet[t] = b; sb[t] = sinf(b); cb[t] = cosf(b);
  }
  __syncthreads();
#pragma unroll
  for (int i = 0; i < 16; ++i) {
    int c = t + 256 * i;
    int row = c >> 7, n = c & 127;
    float acc = b_emb[n];
#pragma unroll
    for (int k = 0; k < 8; ++k) acc += Hs[row * 8 + k] * W_emb[k * 128 + n];
    acc += bet[row] * W_emb[8 * 128 + n] + sb[row] * W_emb[9 * 128 + n]
         + cb[row] * W_emb[10 * 128 + n];
    hns[row * 132 + n] = acc;
    h[(r0 + row) * 128 + n] = acc;
  }
  __syncthreads();
  pq_stage(hns, We1T0, be1_0, Pp, Qb, r0, t);
}

// ---------------- edge kernel: r10 EXACT (best measured: 100.9 total) ----------
// grid = 48 graphs x 16 atiles (4 a-rows); block = 512 thr = 4 a-rows x 2 b-halves.
// LDS 57.4KB -> 2 blocks/CU = 4 waves/SIMD; waves_per_eu(4,4) pins the 128-VGPR
// operating point. Verdict after r11-r15 experiments: every alternative (fusion,
// 6 waves/EU via LDS diet or restage, full-b waves, 16x16 MFMA, node resplit)
// regressed or was neutral -> this is the measured optimum for this structure.
__global__ __launch_bounds__(512)
__attribute__((amdgpu_waves_per_eu(4, 4)))
void edge_kernel(
    const float* __restrict__ Ppin, const __bf16* __restrict__ Qbin,
    const float* __restrict__ Z, const float* __restrict__ wvg,
    const __bf16* __restrict__ We2Tl, const float* __restrict__ be2l,
    float* __restrict__ agg) {
  __shared__ __bf16 Qs[64 * 132];     // 16.9 KB
  __shared__ __bf16 WeTs[128 * 132];  // 33.8 KB
  __shared__ float  Ps[4 * 132];      // prescaled P'' rows (incl. be1, *ALPHA)
  __shared__ float  aggp[8][132];     // per-wave partial agg
  __shared__ float  Zs[192];
  __shared__ float  wvs[128];         // prescaled d2-weight row
  __shared__ float  be2s[128];        // ALPHA*be2
  int t = threadIdx.x;
  int g = blockIdx.x >> 4, atile = blockIdx.x & 15;
  int a0 = atile * 4, gn0 = g * 64;
#pragma unroll
  for (int i = 0; i < 2; ++i) {
    int c = t + 512 * i; int row = c >> 4, c8 = (c & 15) * 8;
    *(uint4*)&Qs[row * 132 + c8] = *(const uint4*)&Qbin[(gn0 + row) * 128 + c8];
  }
#pragma unroll
  for (int i = 0; i < 4; ++i) {
    int c = t + 512 * i; int row = c >> 4, c8 = (c & 15) * 8;
    *(uint4*)&WeTs[row * 132 + c8] = *(const uint4*)&We2Tl[row * 128 + c8];
  }
  if (t < 128) {
    int row = t >> 5, c4 = (t & 31) * 4;
    *(float4*)&Ps[row * 132 + c4] = *(const float4*)&Ppin[(gn0 + a0 + row) * 128 + c4];
    wvs[t] = wvg[t];
    be2s[t] = ALPHA * be2l[t];
  }
  if (t < 192) Zs[t] = Z[gn0 * 3 + t];
  __syncthreads();

  int lane = t & 63, wid = t >> 6, l31 = lane & 31, q = lane >> 5;
  int a_loc = wid >> 1, bhalf = wid & 1;
  int a_g = a0 + a_loc;
  int b = bhalf * 32 + l31;

  float zax = Zs[a_g * 3], zay = Zs[a_g * 3 + 1], zaz = Zs[a_g * 3 + 2];
  float dx = zax - Zs[b * 3], dy = zay - Zs[b * 3 + 1], dz = zaz - Zs[b * 3 + 2];
  float d2 = dx * dx + dy * dy + dz * dz;

  // build m1 A-fragments: m1[b][k] = ssilu(P'' + Q'' + d2*w'')
  bf16x8 af[8];
#pragma unroll
  for (int kk = 0; kk < 8; ++kk) {
    int k0 = kk * 16 + q * 8;
    float4 pv0 = *(const float4*)&Ps[a_loc * 132 + k0];
    float4 pv1 = *(const float4*)&Ps[a_loc * 132 + k0 + 4];
    float4 wv0 = *(const float4*)&wvs[k0];
    float4 wv1 = *(const float4*)&wvs[k0 + 4];
    bf16x8 qv = *(const bf16x8*)&Qs[b * 132 + k0];
#pragma unroll
    for (int j = 0; j < 4; ++j) {
      af[kk][j]     = (__bf16)ssilu(fmaf(d2, wv0[j], pv0[j]) + (float)qv[j]);
      af[kk][j + 4] = (__bf16)ssilu(fmaf(d2, wv1[j], pv1[j]) + (float)qv[j + 4]);
    }
  }
  // nt tiles in pairs (two f32x16 accs live at a time), B-fragments from LDS
  float smv[4];
#pragma unroll
  for (int np = 0; np < 2; ++np) {
    f32x16 accA, accB;
#pragma unroll
    for (int r = 0; r < 16; ++r) { accA[r] = 0.f; accB[r] = 0.f; }
#pragma unroll
    for (int kk = 0; kk < 8; ++kk) {
      int ko = kk * 16 + q * 8;
      accA = MFMA(af[kk], *(const bf16x8*)&WeTs[((np * 2 + 0) * 32 + l31) * 132 + ko], accA);
      accB = MFMA(af[kk], *(const bf16x8*)&WeTs[((np * 2 + 1) * 32 + l31) * 132 + ko], accB);
    }
    float bbA = be2s[(np * 2 + 0) * 32 + l31], bbB = be2s[(np * 2 + 1) * 32 + l31];
    float sA0 = 0.f, sA1 = 0.f, sB0 = 0.f, sB1 = 0.f;
#pragma unroll
    for (int r = 0; r < 8; ++r) {
      sA0 += ssilu(accA[r] + bbA); sA1 += ssilu(accA[r + 8] + bbA);
      sB0 += ssilu(accB[r] + bbB); sB1 += ssilu(accB[r + 8] + bbB);
    }
    float sA = sA0 + sA1; sA += __shfl_xor(sA, 32); smv[np * 2 + 0] = sA;
    float sB = sB0 + sB1; sB += __shfl_xor(sB, 32); smv[np * 2 + 1] = sB;
  }
  if (q == 0) {
#pragma unroll
    for (int nt = 0; nt < 4; ++nt)
      aggp[wid][nt * 32 + l31] = smv[nt];   // partial ALPHA*agg
  }
  __syncthreads();
  // combine the two b-half partials, write agg rows (= ALPHA*agg)
  {
    int row = t >> 7, n = t & 127;   // 4 rows x 128 cols = 512 threads
    agg[(gn0 + a0 + row) * 128 + n] = aggp[row * 2 + 0][n] + aggp[row * 2 + 1][n];
  }
}

// ---------------- node update (32 rows/block) + next-layer P/Q ----------------
__global__ __launch_bounds__(256) void node_kernel(
    const float* __restrict__ h, const float* __restrict__ agg,
    const __bf16* __restrict__ Wn1Tl, const float* __restrict__ bn1l,
    const __bf16* __restrict__ Wn2Tl, const float* __restrict__ bn2l,
    const __bf16* __restrict__ We1Tn, const float* __restrict__ be1n,
    float* __restrict__ hout, float* __restrict__ Pp, __bf16* __restrict__ Qb,
    int do_pq) {
  __shared__ float A1s[32 * 260];   // [h | ALPHA*agg] rows
  __shared__ float T1s[32 * 132];
  __shared__ float hns[32 * 132];
  int t = threadIdx.x; int r0 = blockIdx.x * 32;
  int lane = t & 63, wid = t >> 6, l31 = lane & 31, q = lane >> 5;
#pragma unroll
  for (int i = 0; i < 8; ++i) {
    int c = t + 256 * i;              // 2048 float4 chunks
    int row = c >> 6, c4 = (c & 63) * 4;
    const float* src = (c4 < 128) ? &h[(r0 + row) * 128 + c4]
                                  : &agg[(r0 + row) * 128 + c4 - 128];
    *(float4*)&A1s[row * 260 + c4] = *(const float4*)src;
  }
  __syncthreads();
  // stage 1: T1 = silu([h,agg]@Wn1 + bn1), K=256 (agg half of Wn1T pre-scaled LN2)
  {
    f32x16 acc;
#pragma unroll
    for (int r = 0; r < 16; ++r) acc[r] = 0.f;
#pragma unroll
    for (int kk = 0; kk < 16; ++kk) {
      int k0 = kk * 16 + q * 8;
      bf16x8 a; const float* ap = &A1s[l31 * 260 + k0];
#pragma unroll
      for (int j = 0; j < 8; ++j) a[j] = (__bf16)ap[j];
      bf16x8 b = *(const bf16x8*)&Wn1Tl[(wid * 32 + l31) * 256 + k0];
      acc = MFMA(a, b, acc);
    }
    int col = wid * 32 + l31; float bb = bn1l[col];
#pragma unroll
    for (int reg = 0; reg < 16; ++reg) {
      int rr = (reg & 3) + 8 * (reg >> 2) + 4 * q;
      T1s[rr * 132 + col] = fsilu(acc[reg] + bb);
    }
  }
  __syncthreads();
  // stage 2: h_new = h + T1@Wn2 + bn2
  {
    f32x16 acc;
#pragma unroll
    for (int r = 0; r < 16; ++r) acc[r] = 0.f;
#pragma unroll
    for (int kk = 0; kk < 8; ++kk) {
      int k0 = kk * 16 + q * 8;
      bf16x8 a; const float* ap = &T1s[l31 * 132 + k0];
#pragma unroll
      for (int j = 0; j < 8; ++j) a[j] = (__bf16)ap[j];
      bf16x8 b = *(const bf16x8*)&Wn2Tl[(wid * 32 + l31) * 128 + k0];
      acc = MFMA(a, b, acc);
    }
    int col = wid * 32 + l31; float bb = bn2l[col];
#pragma unroll
    for (int reg = 0; reg < 16; ++reg) {
      int rr = (reg & 3) + 8 * (reg >> 2) + 4 * q;
      float v = acc[reg] + bb + A1s[rr * 260 + col];
      hns[rr * 132 + col] = v;
      hout[(r0 + rr) * 128 + col] = v;
    }
  }
  __syncthreads();
  if (do_pq) pq_stage(hns, We1Tn, be1n, Pp, Qb, r0, t);
}

// ---------------- readout: segsum/8 -> silu -> Wo1 -> silu -> Wo2 ----------
__global__ __launch_bounds__(256) void readout_kernel(
    const float* h, const float* Wo1, const float* bo1,
    const float* Wo2, const float* bo2, float* out) {
  __shared__ float part[2][128];
  __shared__ float sbuf[128];
  int g = blockIdx.x; int t = threadIdx.x; int n = t & 127, half = t >> 7;
  float acc = 0.f;
#pragma unroll
  for (int r = 0; r < 32; ++r) acc += h[(g * 64 + half * 32 + r) * 128 + n];
  part[half][n] = acc;
  __syncthreads();
  if (half == 0) sbuf[n] = fsilu((part[0][n] + part[1][n]) * 0.125f);
  __syncthreads();
  float o1 = 0.f;
#pragma unroll
  for (int k = 0; k < 64; ++k) o1 += sbuf[half * 64 + k] * Wo1[(half * 64 + k) * 128 + n];
  part[half][n] = o1;
  __syncthreads();
  if (half == 0) sbuf[n] = fsilu(part[0][n] + part[1][n] + bo1[n]);
  __syncthreads();
  float o2 = 0.f;
#pragma unroll
  for (int k = 0; k < 64; ++k) o2 += sbuf[half * 64 + k] * Wo2[(half * 64 + k) * 128 + n];
  part[half][n] = o2;
  __syncthreads();
  if (half == 0) out[g * 128 + n] = part[0][n] + part[1][n] + bo2[n];
}

extern "C" void kernel_launch(void* const* d_in, const int* in_sizes, int n_in,
                              void* d_out, int out_size, void* d_ws, size_t ws_size,
                              hipStream_t stream) {
  (void)in_sizes; (void)n_in; (void)out_size; (void)ws_size;
  const float* H     = (const float*)d_in[0];
  const float* Z     = (const float*)d_in[1];
  const float* beta  = (const float*)d_in[2];
  const float* W_emb = (const float*)d_in[5];
  const float* b_emb = (const float*)d_in[6];
  const float* We1   = (const float*)d_in[7];
  const float* be1   = (const float*)d_in[8];
  const float* We2   = (const float*)d_in[9];
  const float* be2   = (const float*)d_in[10];
  const float* Wn1   = (const float*)d_in[11];
  const float* bn1   = (const float*)d_in[12];
  const float* Wn2   = (const float*)d_in[13];
  const float* bn2   = (const float*)d_in[14];
  const float* Wo1   = (const float*)d_in[15];
  const float* bo1   = (const float*)d_in[16];
  const float* Wo2   = (const float*)d_in[17];
  const float* bo2   = (const float*)d_in[18];

  char* ws = (char*)d_ws;
  float*  h    = (float*)(ws + 0);          // 1.57 MB
  float*  Pp   = (float*)(ws + 1572864);    // 1.57 MB (single-buffered: kernels serialize)
  float*  agg  = (float*)(ws + 3145728);    // 1.57 MB
  __bf16* Qb   = (__bf16*)(ws + 4718592);   // 0.79 MB
  __bf16* We1T = (__bf16*)(ws + 5505024);
  __bf16* We2T = (__bf16*)(ws + 5701632);
  __bf16* Wn1T = (__bf16*)(ws + 5799936);
  __bf16* Wn2T = (__bf16*)(ws + 5996544);
  float*  wv   = (float*)(ws + 6094848);

  prep_kernel<<<1154, 256, 0, stream>>>(We1, We2, Wn1, Wn2, We1T, We2T, Wn1T, Wn2T, wv);
  embed_kernel<<<96, 256, 0, stream>>>(H, beta, W_emb, b_emb, We1T, be1, h, Pp, Qb);

  for (int l = 0; l < 3; ++l) {
    edge_kernel<<<NGRAPH * 16, 512, 0, stream>>>(
        Pp, Qb, Z, wv + l * 128, We2T + l * 128 * 128, be2 + l * 128, agg);
    int dopq = (l < 2) ? 1 : 0;
    node_kernel<<<96, 256, 0, stream>>>(
        h, agg, Wn1T + l * 128 * 256, bn1 + l * 128, Wn2T + l * 128 * 128, bn2 + l * 128,
        We1T + (dopq ? (l + 1) * 256 * 128 : 0), be1 + (dopq ? (l + 1) * 128 : 0),
        h, Pp, Qb, dopq);
  }
  readout_kernel<<<NGRAPH, 256, 0, stream>>>(h, Wo1, bo1, Wo2, bo2, (float*)d_out);
}